// Round 2
// baseline (370.241 us; speedup 1.0000x reference)
//
#include <hip/hip_runtime.h>

#define NBINS 8192            // 13-bit top bits of sortable key: sign+exp+4 mantissa
#define FB_THREADS 1024
#define FB_BLOCKS 256         // 1 block/CU (128 KB LDS), grid-stride

// Monotone float -> uint map (ascending). Larger curvature -> larger key.
__device__ __forceinline__ unsigned sortable_key(float f) {
  unsigned u = __float_as_uint(f);
  return u ^ ((u & 0x80000000u) ? 0xFFFFFFFFu : 0x80000000u);
}

__device__ __forceinline__ void bin_accum(float* __restrict__ h,
                                          float cj, float xj, float tj) {
  unsigned bin = sortable_key(cj) >> 19;
  float p = __fdividef(1.f, 1.f + __expf(-xj));
  atomicAdd(&h[bin], 1.0f);             // count (exact in f32: < 2^24)
  atomicAdd(&h[NBINS + bin], p);
  atomicAdd(&h[2 * NBINS + bin], tj);
  atomicAdd(&h[3 * NBINS + bin], p * tj);
}

__device__ __forceinline__ void bin_accum4(float* __restrict__ h,
                                           float4 c, float4 x, float4 t) {
  bin_accum(h, c.x, x.x, t.x);
  bin_accum(h, c.y, x.y, t.y);
  bin_accum(h, c.z, x.z, t.z);
  bin_accum(h, c.w, x.w, t.w);
}

// Single pass over all three arrays: per-bin (count, sum_p, sum_t, sum_pt).
__global__ void __launch_bounds__(FB_THREADS, 1) fused_kernel(
    const float* __restrict__ xin, const float* __restrict__ tin,
    const float* __restrict__ cin, float* __restrict__ gb,
    int nvec, int ntail) {
  __shared__ float h[4 * NBINS];  // SoA: [comp][bin] -> banks spread by bin
  for (int i = threadIdx.x; i < 4 * NBINS; i += FB_THREADS) h[i] = 0.f;
  __syncthreads();

  const float4* __restrict__ x4 = (const float4*)xin;
  const float4* __restrict__ t4 = (const float4*)tin;
  const float4* __restrict__ c4 = (const float4*)cin;

  int idx = blockIdx.x * FB_THREADS + threadIdx.x;
  int stride = gridDim.x * FB_THREADS;
  int i = idx;
  // unroll x4: issue all 12 loads before consuming (latency hiding)
  for (; i + 3 * stride < nvec; i += 4 * stride) {
    float4 c0 = c4[i];
    float4 c1 = c4[i + stride];
    float4 c2 = c4[i + 2 * stride];
    float4 c3 = c4[i + 3 * stride];
    float4 x0 = x4[i];
    float4 x1 = x4[i + stride];
    float4 x2 = x4[i + 2 * stride];
    float4 x3 = x4[i + 3 * stride];
    float4 t0 = t4[i];
    float4 t1 = t4[i + stride];
    float4 t2 = t4[i + 2 * stride];
    float4 t3 = t4[i + 3 * stride];
    bin_accum4(h, c0, x0, t0);
    bin_accum4(h, c1, x1, t1);
    bin_accum4(h, c2, x2, t2);
    bin_accum4(h, c3, x3, t3);
  }
  for (; i < nvec; i += stride) {
    bin_accum4(h, c4[i], x4[i], t4[i]);
  }
  if (idx == 0) {  // scalar tail (N % 4)
    for (int e = nvec * 4; e < nvec * 4 + ntail; ++e)
      bin_accum(h, cin[e], xin[e], tin[e]);
  }
  __syncthreads();

  // merge nonzero bins to global (spread over ~4K addresses)
  for (int b = threadIdx.x; b < NBINS; b += FB_THREADS) {
    float cnt = h[b];
    if (cnt != 0.f) {
      atomicAdd(&gb[b], cnt);
      atomicAdd(&gb[NBINS + b], h[NBINS + b]);
      atomicAdd(&gb[2 * NBINS + b], h[2 * NBINS + b]);
      atomicAdd(&gb[3 * NBINS + b], h[3 * NBINS + b]);
    }
  }
}

// One block: find boundary bin via suffix scan of counts, then weighted
// f64 reduction of per-bin sums, write final dice loss.
__global__ void __launch_bounds__(1024) final_kernel(
    const float* __restrict__ gb, unsigned K, float* __restrict__ out) {
  __shared__ unsigned waveTot[16];
  __shared__ unsigned waveSuf[16];
  __shared__ unsigned s_bsel;
  __shared__ float s_frac;
  __shared__ double wsum[3][16];

  int tid = threadIdx.x;
  int lane = tid & 63;
  int wid = tid >> 6;

  // each thread owns 8 consecutive bins
  unsigned base = tid * 8;
  unsigned c[8];
  unsigned cs = 0;
#pragma unroll
  for (int i = 0; i < 8; ++i) {
    c[i] = (unsigned)(gb[base + i] + 0.5f);
    cs += c[i];
  }

  // wave-level inclusive suffix sum of chunk totals
  unsigned incl = cs;
#pragma unroll
  for (int off = 1; off < 64; off <<= 1) {
    unsigned o = __shfl_down(incl, off);
    if (lane + off < 64) incl += o;
  }
  if (lane == 0) waveTot[wid] = incl;
  __syncthreads();
  if (tid == 0) {
    unsigned run = 0;
    for (int w = 15; w >= 0; --w) { waveSuf[w] = run; run += waveTot[w]; }
  }
  __syncthreads();

  // elements in bins strictly above this thread's chunk
  unsigned above = waveSuf[wid] + (incl - cs);
  unsigned run = above;
#pragma unroll
  for (int i = 7; i >= 0; --i) {  // high -> low within chunk
    unsigned cc = c[i];
    if (cc && run < K && run + cc >= K) {  // unique crossing
      s_bsel = base + (unsigned)i;
      s_frac = (float)((double)(K - run) / (double)cc);
    }
    run += cc;
  }
  __syncthreads();

  unsigned bsel = s_bsel;
  double frac = (double)s_frac;

  double sp = 0, st = 0, spt = 0;
#pragma unroll
  for (int i = 0; i < 8; ++i) {
    unsigned b = base + i;
    double w = (b > bsel) ? 1.0 : ((b == bsel) ? frac : 0.0);
    if (w != 0.0) {
      sp  += w * (double)gb[NBINS + b];
      st  += w * (double)gb[2 * NBINS + b];
      spt += w * (double)gb[3 * NBINS + b];
    }
  }
#pragma unroll
  for (int off = 32; off > 0; off >>= 1) {
    sp  += __shfl_down(sp, off);
    st  += __shfl_down(st, off);
    spt += __shfl_down(spt, off);
  }
  if (lane == 0) { wsum[0][wid] = sp; wsum[1][wid] = st; wsum[2][wid] = spt; }
  __syncthreads();
  if (tid == 0) {
    double a = 0, b = 0, cc = 0;
#pragma unroll
    for (int w = 0; w < 16; ++w) {
      a += wsum[0][w]; b += wsum[1][w]; cc += wsum[2][w];
    }
    double dice = (2.0 * cc + 1.0) / (a + b + 1.0);
    out[0] = (float)(1.0 - dice);
  }
}

extern "C" void kernel_launch(void* const* d_in, const int* in_sizes, int n_in,
                              void* d_out, int out_size, void* d_ws, size_t ws_size,
                              hipStream_t stream) {
  const float* d_inputs  = (const float*)d_in[0];
  const float* d_targets = (const float*)d_in[1];
  const float* d_curv    = (const float*)d_in[2];
  float* out = (float*)d_out;

  int N = in_sizes[2];
  unsigned K = (unsigned)(0.4 * (double)N);  // matches Python int(R*N)

  float* gb = (float*)d_ws;  // 4 * NBINS floats

  // zero merged bins every call (harness doesn't re-poison d_ws)
  hipMemsetAsync(d_ws, 0, 4 * NBINS * sizeof(float), stream);

  int nvec = N / 4;
  int ntail = N - nvec * 4;

  fused_kernel<<<FB_BLOCKS, FB_THREADS, 0, stream>>>(d_inputs, d_targets,
                                                     d_curv, gb, nvec, ntail);
  final_kernel<<<1, 1024, 0, stream>>>(gb, K, out);
}

// Round 3
// 77.273 us; speedup vs baseline: 4.7913x; 4.7913x over previous
//
#include <hip/hip_runtime.h>

#define NBINS 8192            // 13-bit top bits of sortable key
#define HIST_BLOCKS 1024
#define HIST_THREADS 256
#define SUM_BLOCKS 2048
#define SUM_THREADS 256

struct Control {
  unsigned bsel;
  float frac;
};

// Monotone float -> uint map (ascending). Larger curvature -> larger key.
__device__ __forceinline__ unsigned sortable_key(float f) {
  unsigned u = __float_as_uint(f);
  return u ^ ((u & 0x80000000u) ? 0xFFFFFFFFu : 0x80000000u);
}

__global__ void __launch_bounds__(HIST_THREADS) hist_kernel(
    const float* __restrict__ cv, unsigned* __restrict__ hist,
    int nvec, int ntail) {
  __shared__ unsigned h[NBINS];
  for (int i = threadIdx.x; i < NBINS; i += blockDim.x) h[i] = 0;
  __syncthreads();

  const float4* __restrict__ c4 = (const float4*)cv;
  int idx = blockIdx.x * blockDim.x + threadIdx.x;
  int stride = gridDim.x * blockDim.x;
  for (int i = idx; i < nvec; i += stride) {
    float4 v = c4[i];
    atomicAdd(&h[sortable_key(v.x) >> 19], 1u);
    atomicAdd(&h[sortable_key(v.y) >> 19], 1u);
    atomicAdd(&h[sortable_key(v.z) >> 19], 1u);
    atomicAdd(&h[sortable_key(v.w) >> 19], 1u);
  }
  if (idx == 0) {
    for (int i = 0; i < ntail; ++i)
      atomicAdd(&hist[sortable_key(cv[nvec * 4 + i]) >> 19], 1u);
  }
  __syncthreads();
  for (int i = threadIdx.x; i < NBINS; i += blockDim.x) {
    unsigned c = h[i];
    if (c) atomicAdd(&hist[i], c);  // most bins empty -> skip
  }
}

// One block, 1024 threads: suffix-scan histogram from the top, find the
// bin where the cumulative count crosses K; frac weights the boundary bin.
__global__ void __launch_bounds__(1024) select_kernel(
    const unsigned* __restrict__ hist, Control* __restrict__ ctl, unsigned K) {
  __shared__ unsigned waveTot[16];
  __shared__ unsigned waveSuf[16];
  int tid = threadIdx.x;
  int lane = tid & 63;
  int wid = tid >> 6;

  unsigned base = tid * 8;
  unsigned c[8];
  unsigned cs = 0;
#pragma unroll
  for (int i = 0; i < 8; ++i) { c[i] = hist[base + i]; cs += c[i]; }

  unsigned incl = cs;
#pragma unroll
  for (int off = 1; off < 64; off <<= 1) {
    unsigned o = __shfl_down(incl, off);
    if (lane + off < 64) incl += o;
  }
  if (lane == 0) waveTot[wid] = incl;
  __syncthreads();
  if (tid == 0) {
    unsigned run = 0;
    for (int w = 15; w >= 0; --w) { waveSuf[w] = run; run += waveTot[w]; }
  }
  __syncthreads();

  unsigned above = waveSuf[wid] + (incl - cs);
  unsigned run = above;
#pragma unroll
  for (int i = 7; i >= 0; --i) {  // high -> low within chunk
    unsigned cc = c[i];
    if (cc && run < K && run + cc >= K) {  // unique crossing
      ctl->bsel = base + (unsigned)i;
      ctl->frac = (float)((double)(K - run) / (double)cc);
    }
    run += cc;
  }
}

// Weighted sums; per-block partials to DISTINCT slots (no atomics).
__global__ void __launch_bounds__(SUM_THREADS) sum_kernel(
    const float* __restrict__ xin, const float* __restrict__ tin,
    const float* __restrict__ cin, const Control* __restrict__ ctl,
    float* __restrict__ partials,  // SoA: [3][SUM_BLOCKS]
    int nvec, int ntail) {
  const unsigned bsel = ctl->bsel;
  const float frac = ctl->frac;

  const float4* __restrict__ x4 = (const float4*)xin;
  const float4* __restrict__ t4 = (const float4*)tin;
  const float4* __restrict__ c4 = (const float4*)cin;

  float sp = 0.f, st = 0.f, spt = 0.f;
  int idx = blockIdx.x * SUM_THREADS + threadIdx.x;
  int stride = gridDim.x * SUM_THREADS;
  int i = idx;
  for (; i + stride < nvec; i += 2 * stride) {  // x2 unroll: 6 loads in flight
    float4 c0 = c4[i];
    float4 c1 = c4[i + stride];
    float4 x0 = x4[i];
    float4 x1 = x4[i + stride];
    float4 t0 = t4[i];
    float4 t1 = t4[i + stride];
#pragma unroll
    for (int j = 0; j < 4; ++j) {
      float cj = (&c0.x)[j], xj = (&x0.x)[j], tj = (&t0.x)[j];
      unsigned bin = sortable_key(cj) >> 19;
      float w = (bin > bsel) ? 1.f : ((bin == bsel) ? frac : 0.f);
      float p = __fdividef(1.f, 1.f + __expf(-xj));
      sp += w * p; st += w * tj; spt += w * p * tj;
    }
#pragma unroll
    for (int j = 0; j < 4; ++j) {
      float cj = (&c1.x)[j], xj = (&x1.x)[j], tj = (&t1.x)[j];
      unsigned bin = sortable_key(cj) >> 19;
      float w = (bin > bsel) ? 1.f : ((bin == bsel) ? frac : 0.f);
      float p = __fdividef(1.f, 1.f + __expf(-xj));
      sp += w * p; st += w * tj; spt += w * p * tj;
    }
  }
  for (; i < nvec; i += stride) {
    float4 cv = c4[i], xv = x4[i], tv = t4[i];
#pragma unroll
    for (int j = 0; j < 4; ++j) {
      float cj = (&cv.x)[j], xj = (&xv.x)[j], tj = (&tv.x)[j];
      unsigned bin = sortable_key(cj) >> 19;
      float w = (bin > bsel) ? 1.f : ((bin == bsel) ? frac : 0.f);
      float p = __fdividef(1.f, 1.f + __expf(-xj));
      sp += w * p; st += w * tj; spt += w * p * tj;
    }
  }
  if (idx == 0) {  // scalar tail (N % 4)
    for (int e = nvec * 4; e < nvec * 4 + ntail; ++e) {
      unsigned bin = sortable_key(cin[e]) >> 19;
      float w = (bin > bsel) ? 1.f : ((bin == bsel) ? frac : 0.f);
      float p = __fdividef(1.f, 1.f + __expf(-xin[e]));
      sp += w * p; st += w * tin[e]; spt += w * p * tin[e];
    }
  }

#pragma unroll
  for (int off = 32; off > 0; off >>= 1) {
    sp  += __shfl_down(sp, off);
    st  += __shfl_down(st, off);
    spt += __shfl_down(spt, off);
  }
  __shared__ float wsum[3][SUM_THREADS / 64];
  int lane = threadIdx.x & 63;
  int wid = threadIdx.x >> 6;
  if (lane == 0) { wsum[0][wid] = sp; wsum[1][wid] = st; wsum[2][wid] = spt; }
  __syncthreads();
  if (threadIdx.x == 0) {
    float a = 0.f, b = 0.f, c = 0.f;
#pragma unroll
    for (int w = 0; w < SUM_THREADS / 64; ++w) {
      a += wsum[0][w]; b += wsum[1][w]; c += wsum[2][w];
    }
    partials[blockIdx.x]                  = a;
    partials[SUM_BLOCKS + blockIdx.x]     = b;
    partials[2 * SUM_BLOCKS + blockIdx.x] = c;
  }
}

// Deterministic f64 reduction of the per-block partials + dice.
__global__ void __launch_bounds__(1024) reduce_kernel(
    const float* __restrict__ partials, float* __restrict__ out) {
  __shared__ double wsum[3][16];
  int tid = threadIdx.x;
  int lane = tid & 63;
  int wid = tid >> 6;

  double sp = 0, st = 0, spt = 0;
  for (int j = tid; j < SUM_BLOCKS; j += 1024) {
    sp  += (double)partials[j];
    st  += (double)partials[SUM_BLOCKS + j];
    spt += (double)partials[2 * SUM_BLOCKS + j];
  }
#pragma unroll
  for (int off = 32; off > 0; off >>= 1) {
    sp  += __shfl_down(sp, off);
    st  += __shfl_down(st, off);
    spt += __shfl_down(spt, off);
  }
  if (lane == 0) { wsum[0][wid] = sp; wsum[1][wid] = st; wsum[2][wid] = spt; }
  __syncthreads();
  if (tid == 0) {
    double a = 0, b = 0, c = 0;
#pragma unroll
    for (int w = 0; w < 16; ++w) { a += wsum[0][w]; b += wsum[1][w]; c += wsum[2][w]; }
    double dice = (2.0 * c + 1.0) / (a + b + 1.0);
    out[0] = (float)(1.0 - dice);
  }
}

extern "C" void kernel_launch(void* const* d_in, const int* in_sizes, int n_in,
                              void* d_out, int out_size, void* d_ws, size_t ws_size,
                              hipStream_t stream) {
  const float* d_inputs  = (const float*)d_in[0];
  const float* d_targets = (const float*)d_in[1];
  const float* d_curv    = (const float*)d_in[2];
  float* out = (float*)d_out;

  int N = in_sizes[2];
  unsigned K = (unsigned)(0.4 * (double)N);  // matches Python int(R*N)

  unsigned* hist = (unsigned*)d_ws;                          // 32 KB
  Control* ctl   = (Control*)((char*)d_ws + NBINS * 4);      // 32 B
  float* partials = (float*)((char*)d_ws + NBINS * 4 + 32);  // 24 KB

  // zero the histogram every call (harness doesn't re-poison d_ws)
  hipMemsetAsync(d_ws, 0, NBINS * 4 + 32, stream);

  int nvec = N / 4;
  int ntail = N - nvec * 4;

  hist_kernel<<<HIST_BLOCKS, HIST_THREADS, 0, stream>>>(d_curv, hist, nvec, ntail);
  select_kernel<<<1, 1024, 0, stream>>>(hist, ctl, K);
  sum_kernel<<<SUM_BLOCKS, SUM_THREADS, 0, stream>>>(d_inputs, d_targets, d_curv,
                                                     ctl, partials, nvec, ntail);
  reduce_kernel<<<1, 1024, 0, stream>>>(partials, out);
}